// Round 2
// baseline (413.468 us; speedup 1.0000x reference)
//
#include <hip/hip_runtime.h>

#define XDIM 256
#define YDIM 256
#define ZDIM 32
#define NT 384
#define NA 180
#define AG 6                      // angles per block (180/6=30 groups)
#define STRIDE 263                // dwords per LDS row; ODD => axis angles spread all 32 banks
#define NROWSL 133                // LDS rows per phase
#define SL_DWORDS (NROWSL * STRIDE)      // 34979
#define SL_DWORDS_PAD 34980
#define SL_BYTES (SL_DWORDS_PAD * 4)     // 139920
#define PSUM_BYTES 4096
#define SMEM_BYTES (SL_BYTES + PSUM_BYTES)  // 144016 < 160K

// Two y-phases per block: phase 0 stages volume rows [-3..128] (real 0..128),
// phase 1 rows [126..258] (real 126..255); 3 zero border rows + 7 zero border
// cols give reference's boundary-weight-zeroing for free, and one real guard
// row on each side of the y=127 partition makes +-1-sample float misassignment
// still exact. f32 staging => (v00,v01) and (v10,v11) are adjacent dwords ->
// ds_read2_b32 pairs: 2 LDS instructions per bilinear sample instead of 4.
__global__ __launch_bounds__(1024) void proj_kernel(
    const float* __restrict__ vol,
    const float* __restrict__ phis,
    float* __restrict__ out) {
  extern __shared__ char smem[];
  float* sl = reinterpret_cast<float*>(smem);
  float* psum = reinterpret_cast<float*>(smem + SL_BYTES);

  const int tid = threadIdx.x;
  const int z = blockIdx.x;   // 0..31
  const int ag = blockIdx.y;  // 0..29

  const int col = tid & 255;
  const int q = tid >> 8;  // t-quarter, interleaved mod 4 for load balance
  const float u = (float)col - 127.5f;

  float acc[AG];
#pragma unroll
  for (int j = 0; j < AG; ++j) acc[j] = 0.f;

  const float* src = vol + z * (YDIM * XDIM);
  const float4* src4 = reinterpret_cast<const float4*>(src);

  for (int ph = 0; ph < 2; ++ph) {
    __syncthreads();  // previous phase's readers done before we overwrite LDS

    const int rlo = ph ? 126 : 0;    // first real volume row staged
    const int nr = ph ? 130 : 129;   // number of real rows
    const int ro = ph ? 0 : 3;       // Ly of first real row (rlo - R0)
    // full zero rows (contiguous in LDS): p0 Ly 0..2 (rows -3..-1), p1 Ly 130..132 (rows 256..258)
    {
      int zb = (ph ? 130 : 0) * STRIDE;
      for (int k = tid; k < 3 * STRIDE; k += 1024) sl[zb + k] = 0.f;
    }
    // side pad cols (Lx 0,1,2 and 259..262) for every row; never touches real cells
    for (int k = tid; k < NROWSL * 7; k += 1024) {
      int r = k / 7;
      int ci = k - r * 7;
      int Lx = ci < 3 ? ci : 256 + ci;
      sl[r * STRIDE + Lx] = 0.f;
    }
    // real rows, coalesced float4 reads; LDS rows unaligned (odd stride) -> scalar stores
    for (int k = tid; k < nr * 64; k += 1024) {
      int r = k >> 6, cg = k & 63;
      float4 v = src4[(rlo + r) * 64 + cg];
      float* d = sl + (r + ro) * STRIDE + 3 + cg * 4;
      d[0] = v.x; d[1] = v.y; d[2] = v.z; d[3] = v.w;
    }
    __syncthreads();

    // idx offset: Ly*STRIDE+Lx = y0f*STRIDE + x0f + (3 - R0*STRIDE)
    const int KP = ph ? (3 - 126 * STRIDE) : (3 + 3 * STRIDE);

    for (int j = 0; j < AG; ++j) {
      const int a = ag * AG + j;
      const float phi = phis[a] * 0.017453292519943295f;
      const float c = cosf(phi);
      const float s = sinf(phi);
      const float bx = fmaf(u, -s, 127.5f);  // ix(t) = bx + t*c, t = it - 191.5
      const float by = fmaf(u, c, 127.5f);   // iy(t) = by + t*s

      // global t-interval where sample can be nonzero (x,y in (-1,256)), widened +-2;
      // every executed sample is exact (zero borders), widening only adds zeros.
      float lo = 0.f, hi = (float)NT;
      {
        if (fabsf(c) < 1e-6f) {
          if (bx <= -1.f || bx >= 256.f) { lo = 1.f; hi = 0.f; }
        } else {
          float t1 = (-1.f - bx) / c + 191.5f;
          float t2 = (256.f - bx) / c + 191.5f;
          lo = fmaxf(lo, fminf(t1, t2) - 2.f);
          hi = fminf(hi, fmaxf(t1, t2) + 2.f);
        }
      }
      {
        if (fabsf(s) < 1e-6f) {
          if (by <= -1.f || by >= 256.f) { lo = 1.f; hi = 0.f; }
        } else {
          float t1 = (-1.f - by) / s + 191.5f;
          float t2 = (256.f - by) / s + 191.5f;
          lo = fmaxf(lo, fminf(t1, t2) - 2.f);
          hi = fminf(hi, fmaxf(t1, t2) + 2.f);
        }
      }
      int itA = (int)fmaxf(lo, 0.f);
      int itB = (int)fminf(hi, (float)NT);

      // partition at y = 127 (y monotone in t); both phases compute identical it*
      if (s > 1e-5f) {
        int its = (int)ceilf((127.f - by) / s + 191.5f);
        if (ph == 0) itB = min(itB, its); else itA = max(itA, its);
      } else if (s < -1e-5f) {
        int its = (int)ceilf((127.f - by) / s + 191.5f);
        if (ph == 0) itA = max(itA, its); else itB = min(itB, its);
      } else {
        if ((by < 127.f) != (ph == 0)) { itA = 1; itB = 0; }
      }

      int start = itA + ((q - itA) & 3);
      float t0 = (float)start - 191.5f;
      float x = fmaf(t0, c, bx);
      float y = fmaf(t0, s, by);
      const float dx = 4.f * c, dy = 4.f * s;
      float a_ = acc[j];
      for (int it = start; it < itB; it += 4) {
        float x0f = floorf(x);
        float y0f = floorf(y);
        float fx = x - x0f;
        float fy = y - y0f;
        int ii = (int)fmaf(y0f, (float)STRIDE, x0f) + KP;  // exact: ints < 2^24
        float v00 = sl[ii];
        float v01 = sl[ii + 1];
        float v10 = sl[ii + STRIDE];
        float v11 = sl[ii + STRIDE + 1];
        float wx0 = 1.f - fx;
        float h0 = fmaf(v01, fx, v00 * wx0);
        float h1 = fmaf(v11, fx, v10 * wx0);
        a_ = fmaf(h0, 1.f - fy, a_);
        a_ = fmaf(h1, fy, a_);
        x += dx;
        y += dy;
      }
      acc[j] = a_;
    }
  }

  // reduce the 4 t-quarters per (angle, col) and write out
#pragma unroll
  for (int j = 0; j < AG; ++j) {
    __syncthreads();
    psum[tid] = acc[j];
    __syncthreads();
    if (tid < 256) {
      int a = ag * AG + j;
      float r = psum[col] + psum[256 + col] + psum[512 + col] + psum[768 + col];
      out[(a * ZDIM + z) * XDIM + col] = r;
    }
  }
}

extern "C" void kernel_launch(void* const* d_in, const int* in_sizes, int n_in,
                              void* d_out, int out_size, void* d_ws, size_t ws_size,
                              hipStream_t stream) {
  const float* vol = (const float*)d_in[0];
  const float* phis = (const float*)d_in[1];
  float* out = (float*)d_out;
  (void)hipFuncSetAttribute((const void*)proj_kernel,
                            hipFuncAttributeMaxDynamicSharedMemorySize,
                            SMEM_BYTES);
  dim3 grid(ZDIM, NA / AG);
  proj_kernel<<<grid, 1024, SMEM_BYTES, stream>>>(vol, phis, out);
}